// Round 13
// baseline (228.069 us; speedup 1.0000x reference)
//
#include <hip/hip_runtime.h>

typedef __bf16 bf16;
typedef __attribute__((ext_vector_type(8))) __bf16 bf16x8;
typedef __attribute__((ext_vector_type(4))) __bf16 bf16x4;
typedef __attribute__((ext_vector_type(4))) float f32x4;
typedef __attribute__((ext_vector_type(4))) short short4v;

#define AS1C(p) ((const __attribute__((address_space(1))) void*)(p))
#define AS3(p)  ((__attribute__((address_space(3))) void*)(p))

static __device__ __forceinline__ f32x4 pv_mfma(bf16x4 a, bf16x4 b, f32x4 c) {
#if __has_builtin(__builtin_amdgcn_mfma_f32_16x16x16bf16_1k)
  return __builtin_amdgcn_mfma_f32_16x16x16bf16_1k(
      __builtin_bit_cast(short4v, a), __builtin_bit_cast(short4v, b), c, 0, 0, 0);
#else
  f32x4 d = c;
  asm("v_mfma_f32_16x16x16_bf16 %0, %1, %2, %0" : "+v"(d) : "v"(a), "v"(b));
  return d;
#endif
}

static __device__ __forceinline__ float fexp2(float x) {
#if __has_builtin(__builtin_amdgcn_exp2f)
  return __builtin_amdgcn_exp2f(x);
#else
  return exp2f(x);
#endif
}
static __device__ __forceinline__ float m3(float a, float b, float c) {
  return fmaxf(fmaxf(a, b), c);
}

// ---------------- cast f32 -> bf16, vectorized ----------------
__global__ void castk(const float* __restrict__ in, bf16* __restrict__ out, long n) {
  long i = ((long)blockIdx.x * blockDim.x + threadIdx.x) * 4;
  if (i >= n) return;
  f32x4 v = *reinterpret_cast<const f32x4*>(in + i);
  bf16x4 o;
  o[0] = (bf16)v[0]; o[1] = (bf16)v[1]; o[2] = (bf16)v[2]; o[3] = (bf16)v[3];
  *reinterpret_cast<bf16x4*>(out + i) = o;
}

// ---------------- GEMM 256x256, BK=64, 8 waves (2Mx4N), 512 thr -------------
// Same verified mechanics as the 128^2 kernel (linear gload_lds dest,
// inverse-swizzled global source, swizzled ds_read; barrier -> stage-early ->
// full compute phase). 64 MFMA/wave/K-step, 1 barrier/K-step, 128KB LDS.
// MODE 0: proj -> f32 C[M][N] (+bias), original orientation.
// MODE 1: Q,K -> [bh][l][hd] bf16x4 stores (swapped operands; Q scaled
//         0.125*log2e). grid.x=8 (cols 0..2047 of Wqkv).
// MODE 2: V -> VT [bh][hd][2048] bf16x4 stores (original orientation).
template<int MODE>
__global__ __launch_bounds__(512, 2)
void gemm8(const bf16* __restrict__ A, const bf16* __restrict__ BT,
           const float* __restrict__ bias, void* __restrict__ Cout,
           int N, int K) {
  __shared__ bf16 As[2][256 * 64];   // 64KB
  __shared__ bf16 Bs[2][256 * 64];   // 64KB
  const int tid = threadIdx.x;
  const int lane = tid & 63;
  const int w = tid >> 6;            // 0..7
  const int wm = w >> 2, wn = w & 3; // 2 x 4 wave grid
  const int g = lane >> 4, q = lane & 15;
  const int row0 = blockIdx.y * 256, col0 = blockIdx.x * 256;

  f32x4 acc[8][4] = {};

  // staging: per matrix 4 x 16B per thread per K-tile; linear LDS dest,
  // pre-swizzled global source (rule 21), row = i*64 + (tid>>3)
  const int sr = tid >> 3;                              // 0..63
  const int scb = ((tid & 7) << 4) ^ ((sr & 7) << 4);   // src col-byte

  auto stage = [&](int k0, int buf) {
    #pragma unroll
    for (int i = 0; i < 4; ++i)
      __builtin_amdgcn_global_load_lds(
          AS1C(A + (long)(row0 + i * 64 + sr) * K + k0 + (scb >> 1)),
          AS3((char*)&As[buf][0] + i * 8192 + tid * 16), 16, 0, 0);
    #pragma unroll
    for (int i = 0; i < 4; ++i)
      __builtin_amdgcn_global_load_lds(
          AS1C(BT + (long)(col0 + i * 64 + sr) * K + k0 + (scb >> 1)),
          AS3((char*)&Bs[buf][0] + i * 8192 + tid * 16), 16, 0, 0);
  };

  stage(0, 0);
  const int NK = K >> 6;
  for (int t = 0; t < NK; ++t) {
    const int cur = t & 1;
    __syncthreads();                         // stage(t) landed; prev readers done
    if (t + 1 < NK) stage((t + 1) << 6, cur ^ 1);  // issue early, lands during compute
    const char* Ab = (const char*)&As[cur][0];
    const char* Bb = (const char*)&Bs[cur][0];
    #pragma unroll
    for (int kk = 0; kk < 2; ++kk) {
      bf16x8 bfrag[4];
      #pragma unroll
      for (int ni = 0; ni < 4; ++ni) {
        int rr = wn * 64 + ni * 16 + q;
        int cb = (kk * 64 + g * 16) ^ ((rr & 7) << 4);
        bfrag[ni] = *reinterpret_cast<const bf16x8*>(Bb + rr * 128 + cb);
      }
      #pragma unroll
      for (int mi = 0; mi < 8; ++mi) {
        int rr = wm * 128 + mi * 16 + q;
        int cb = (kk * 64 + g * 16) ^ ((rr & 7) << 4);
        bf16x8 afrag = *reinterpret_cast<const bf16x8*>(Ab + rr * 128 + cb);
        #pragma unroll
        for (int ni = 0; ni < 4; ++ni) {
          if constexpr (MODE == 1)
            acc[mi][ni] = __builtin_amdgcn_mfma_f32_16x16x32_bf16(bfrag[ni], afrag, acc[mi][ni], 0, 0, 0);
          else
            acc[mi][ni] = __builtin_amdgcn_mfma_f32_16x16x32_bf16(afrag, bfrag[ni], acc[mi][ni], 0, 0, 0);
        }
      }
    }
  }

  if constexpr (MODE == 0) {
    #pragma unroll
    for (int mi = 0; mi < 8; ++mi)
      #pragma unroll
      for (int ni = 0; ni < 4; ++ni) {
        int gcol = col0 + wn * 64 + ni * 16 + q;
        float bv = bias[gcol];
        #pragma unroll
        for (int r = 0; r < 4; ++r) {
          int grow = row0 + wm * 128 + mi * 16 + g * 4 + r;
          reinterpret_cast<float*>(Cout)[(long)grow * N + gcol] = acc[mi][ni][r] + bv;
        }
      }
  } else if constexpr (MODE == 1) {
    const int tt = (int)blockIdx.x >> 2;                 // 0=Q, 1=K
    const int h = ((int)blockIdx.x * 4 + wn) & 15;
    const float qs = (tt == 0) ? 0.125f * 1.44269504f : 1.0f;  // log2e folded
    bf16* outb = reinterpret_cast<bf16*>(Cout) + (tt ? 8388608 : 0);
    #pragma unroll
    for (int ni = 0; ni < 4; ++ni) {
      f32x4 bv = *reinterpret_cast<const f32x4*>(bias + col0 + wn * 64 + ni * 16 + g * 4);
      #pragma unroll
      for (int mi = 0; mi < 8; ++mi) {
        int grow = row0 + wm * 128 + mi * 16 + q;
        int bb = grow >> 11, ll = grow & 2047;
        bf16x4 o;
        #pragma unroll
        for (int r = 0; r < 4; ++r) o[r] = (bf16)((acc[mi][ni][r] + bv[r]) * qs);
        *reinterpret_cast<bf16x4*>(outb + ((long)(bb * 16 + h) * 2048 + ll) * 64 + ni * 16 + g * 4) = o;
      }
    }
  } else {
    const int h = ((int)blockIdx.x * 4 + wn) & 15;
    bf16* outb = reinterpret_cast<bf16*>(Cout);
    #pragma unroll
    for (int ni = 0; ni < 4; ++ni) {
      float bv = bias[col0 + wn * 64 + ni * 16 + q];
      int hd = ni * 16 + q;
      #pragma unroll
      for (int mi = 0; mi < 8; ++mi) {
        int grow = row0 + wm * 128 + mi * 16 + g * 4;
        int bb = grow >> 11, ll = grow & 2047;
        bf16x4 o;
        #pragma unroll
        for (int r = 0; r < 4; ++r) o[r] = (bf16)(acc[mi][ni][r] + bv);
        *reinterpret_cast<bf16x4*>(outb + ((long)(bb * 16 + h) * 64 + hd) * 2048 + ll) = o;
      }
    }
  }
}

// ---------------- causal flash attention: r4 structure + exp2/max3 only ------
// Q,K: [bh][2048][64] bf16 (Q pre-scaled by 0.125*log2e). VT: [bh][64][2048].
// Grid 2048 x 256thr, 4 waves x 16 q-rows, K/V double-buffered LDS,
// one __syncthreads per tile, stage issued right after barrier (r4-verified).
__global__ __launch_bounds__(256, 4)
void attn_fwd(const bf16* __restrict__ Qg, const bf16* __restrict__ Kg,
              const bf16* __restrict__ VTg, bf16* __restrict__ Og) {
  __shared__ bf16 Ks[2][64 * 64];
  __shared__ bf16 Vs[2][64 * 64];
  const int tid = threadIdx.x, lane = tid & 63, w = tid >> 6;
  const int g = lane >> 4, q = lane & 15;

  const int orig = blockIdx.x;
  const int wgid = (orig & 7) * 256 + (orig >> 3);
  const int bh = wgid >> 5;
  const int qt = 31 - (wgid & 31);
  const int bb = bh >> 4, h = bh & 15;
  const long base = (long)bh * (2048 * 64);
  const int qw = qt * 64 + w * 16;
  const int myq = qw + q;

  bf16x8 qf[2];
  qf[0] = *reinterpret_cast<const bf16x8*>(Qg + base + (long)myq * 64 + g * 8);
  qf[1] = *reinterpret_cast<const bf16x8*>(Qg + base + (long)myq * 64 + 32 + g * 8);

  f32x4 accO[4] = {};
  float m = -1e30f, l = 0.f;

  const int srow = tid >> 3;
  const int scb = ((tid & 7) << 4) ^ ((srow & 7) << 4);
  const int nt = qt + 1;

  auto stage = [&](int kt, int buf) {
    #pragma unroll
    for (int i = 0; i < 2; ++i) {
      __builtin_amdgcn_global_load_lds(
          AS1C(Kg + base + (long)(kt * 64 + i * 32 + srow) * 64 + (scb >> 1)),
          AS3((char*)&Ks[buf][0] + i * 4096 + w * 1024), 16, 0, 0);
      __builtin_amdgcn_global_load_lds(
          AS1C(VTg + base + (long)(i * 32 + srow) * 2048 + kt * 64 + (scb >> 1)),
          AS3((char*)&Vs[buf][0] + i * 4096 + w * 1024), 16, 0, 0);
    }
  };

  stage(0, 0);

  for (int kt = 0; kt < nt; ++kt) {
    const int cur = kt & 1;
    __syncthreads();
    if (kt + 1 < nt) stage(kt + 1, cur ^ 1);

    const char* Kb = (const char*)&Ks[cur][0];
    const char* Vb = (const char*)&Vs[cur][0];

    f32x4 sT[4] = {};
    #pragma unroll
    for (int kf = 0; kf < 2; ++kf) {
      #pragma unroll
      for (int a = 0; a < 4; ++a) {
        int r = a * 16 + q;
        int cb = (kf * 64 + g * 16) ^ ((r & 7) << 4);
        bf16x8 kb = *reinterpret_cast<const bf16x8*>(Kb + r * 128 + cb);
        sT[a] = __builtin_amdgcn_mfma_f32_16x16x32_bf16(kb, qf[kf], sT[a], 0, 0, 0);
      }
    }

    if (kt == qt) {
      #pragma unroll
      for (int a = 0; a < 4; ++a)
        #pragma unroll
        for (int r = 0; r < 4; ++r) {
          int kv = kt * 64 + a * 16 + 4 * g + r;
          if (kv > myq) sT[a][r] = -1e30f;
        }
    }

    // max via max3 tree + 2-step butterfly (log2 domain)
    float t0 = m3(sT[0][0], sT[0][1], sT[0][2]);
    float t1 = m3(sT[0][3], sT[1][0], sT[1][1]);
    float t2 = m3(sT[1][2], sT[1][3], sT[2][0]);
    float t3 = m3(sT[2][1], sT[2][2], sT[2][3]);
    float t4 = m3(sT[3][0], sT[3][1], sT[3][2]);
    float vm = fmaxf(m3(t0, t1, t2), m3(t3, t4, sT[3][3]));
    vm = fmaxf(vm, __shfl_xor(vm, 16));
    vm = fmaxf(vm, __shfl_xor(vm, 32));
    float mnew = fmaxf(m, vm);
    float fac = fexp2(m - mnew);
    m = mnew;

    float ps = 0.f;
    bf16x4 pa[4];
    #pragma unroll
    for (int a = 0; a < 4; ++a)
      #pragma unroll
      for (int r = 0; r < 4; ++r) {
        float p = fexp2(sT[a][r] - mnew);
        ps += p;
        pa[a][r] = (bf16)p;
      }
    ps += __shfl_xor(ps, 16);
    ps += __shfl_xor(ps, 32);
    l = l * fac + ps;
    #pragma unroll
    for (int b = 0; b < 4; ++b) accO[b] *= fac;

    #pragma unroll
    for (int a = 0; a < 4; ++a) {
      #pragma unroll
      for (int b = 0; b < 4; ++b) {
        int row = b * 16 + q;
        int cb = (a * 32 + g * 8) ^ ((row & 7) << 4);
        bf16x4 vfrag = *reinterpret_cast<const bf16x4*>(Vb + row * 128 + cb);
        accO[b] = pv_mfma(vfrag, pa[a], accO[b]);
      }
    }
  }

  __syncthreads();
  char* ob = (char*)&Ks[0][0] + w * 2048;
  float rl = 1.0f / l;
  #pragma unroll
  for (int b = 0; b < 4; ++b)
    #pragma unroll
    for (int r = 0; r < 4; ++r) {
      int hd = 16 * b + 4 * g + r;
      int cb = (hd * 2) ^ ((q & 7) << 4);
      *reinterpret_cast<bf16*>(ob + q * 128 + cb) = (bf16)(accO[b][r] * rl);
    }
  asm volatile("s_waitcnt lgkmcnt(0)" ::: "memory");
  __builtin_amdgcn_sched_barrier(0);

  const int rr = lane >> 2, cc = lane & 3;
  #pragma unroll
  for (int half = 0; half < 2; ++half) {
    int hd0 = cc * 16 + half * 8;
    int cb = (hd0 * 2) ^ ((rr & 7) << 4);
    bf16x8 vv = *reinterpret_cast<const bf16x8*>(ob + rr * 128 + cb);
    *reinterpret_cast<bf16x8*>(Og + (long)(bb * 2048 + qw + rr) * 1024 + h * 64 + hd0) = vv;
  }
}

// ---------------- launch ----------------
extern "C" void kernel_launch(void* const* d_in, const int* in_sizes, int n_in,
                              void* d_out, int out_size, void* d_ws, size_t ws_size,
                              hipStream_t stream) {
  (void)in_sizes; (void)n_in; (void)out_size; (void)ws_size;
  const float* x     = (const float*)d_in[0];
  const float* Wqkv  = (const float*)d_in[3];
  const float* bqkv  = (const float*)d_in[4];
  const float* Wproj = (const float*)d_in[5];
  const float* bproj = (const float*)d_in[6];

  bf16* xb     = (bf16*)d_ws;              // 8192*1024
  bf16* Wqkvb  = xb + 8388608;             // 3072*1024
  bf16* Wprojb = Wqkvb + 3145728;          // 1024*1024
  bf16* Qb     = Wprojb + 1048576;         // Q | K | VT : 3 * 8388608
  bf16* Ob     = Qb + 3 * 8388608;         // 8192*1024

  castk<<<8192, 256, 0, stream>>>(x, xb, 8388608);
  castk<<<3072, 256, 0, stream>>>(Wqkv, Wqkvb, 3145728);
  castk<<<1024, 256, 0, stream>>>(Wproj, Wprojb, 1048576);

  // QKV GEMM: Q,K cols (swapped, 256 blocks) | V cols -> VT (128 blocks)
  gemm8<1><<<dim3(8, 32), 512, 0, stream>>>(xb, Wqkvb, bqkv, (void*)Qb, 2048, 1024);
  gemm8<2><<<dim3(4, 32), 512, 0, stream>>>(xb, Wqkvb + (long)2048 * 1024, bqkv + 2048,
                                            (void*)(Qb + 16777216), 1024, 1024);

  // attention: 2048 blocks (32 q-tiles x 64 bh), XCD-swizzled (r4 structure)
  attn_fwd<<<dim3(2048), 256, 0, stream>>>(Qb, Qb + 8388608, Qb + 16777216, Ob);

  // proj GEMM: M=8192, N=1024, K=1024 -> f32 d_out
  gemm8<0><<<dim3(4, 32), 512, 0, stream>>>(Ob, Wprojb, bproj, d_out, 1024, 1024);
}

// Round 14
// 201.440 us; speedup vs baseline: 1.1322x; 1.1322x over previous
//
#include <hip/hip_runtime.h>

typedef __bf16 bf16;
typedef __attribute__((ext_vector_type(8))) __bf16 bf16x8;
typedef __attribute__((ext_vector_type(4))) __bf16 bf16x4;
typedef __attribute__((ext_vector_type(4))) float f32x4;
typedef __attribute__((ext_vector_type(4))) short short4v;

#define AS1C(p) ((const __attribute__((address_space(1))) void*)(p))
#define AS3(p)  ((__attribute__((address_space(3))) void*)(p))

static __device__ __forceinline__ f32x4 pv_mfma(bf16x4 a, bf16x4 b, f32x4 c) {
#if __has_builtin(__builtin_amdgcn_mfma_f32_16x16x16bf16_1k)
  return __builtin_amdgcn_mfma_f32_16x16x16bf16_1k(
      __builtin_bit_cast(short4v, a), __builtin_bit_cast(short4v, b), c, 0, 0, 0);
#else
  f32x4 d = c;
  asm("v_mfma_f32_16x16x16_bf16 %0, %1, %2, %0" : "+v"(d) : "v"(a), "v"(b));
  return d;
#endif
}

static __device__ __forceinline__ float fexp2(float x) {
#if __has_builtin(__builtin_amdgcn_exp2f)
  return __builtin_amdgcn_exp2f(x);
#else
  return exp2f(x);
#endif
}
static __device__ __forceinline__ float m3(float a, float b, float c) {
  return fmaxf(fmaxf(a, b), c);
}

// ---------------- cast f32 -> bf16, vectorized ----------------
__global__ void castk(const float* __restrict__ in, bf16* __restrict__ out, long n) {
  long i = ((long)blockIdx.x * blockDim.x + threadIdx.x) * 4;
  if (i >= n) return;
  f32x4 v = *reinterpret_cast<const f32x4*>(in + i);
  bf16x4 o;
  o[0] = (bf16)v[0]; o[1] = (bf16)v[1]; o[2] = (bf16)v[2]; o[3] = (bf16)v[3];
  *reinterpret_cast<bf16x4*>(out + i) = o;
}

// ---------------- GEMM: C = A * BT^T + bias (verified r4 structure, 128^2) ---
// MODE 0: proj -> f32 C[M][N]. MODE 1: Q,K -> [bh][l][hd] (Q scaled 0.125*log2e).
// MODE 2: V -> VT [bh][hd][2048].
template<int MODE>
__global__ __launch_bounds__(256, 2)
void gemm_bt(const bf16* __restrict__ A, const bf16* __restrict__ BT,
             const float* __restrict__ bias, void* __restrict__ Cout,
             int M, int N, int K) {
  __shared__ bf16 As[128 * 64];
  __shared__ bf16 Bs[128 * 64];
  const int tid = threadIdx.x;
  const int lane = tid & 63;
  const int w = tid >> 6;
  const int wm = w >> 1, wn = w & 1;
  const int row0 = blockIdx.y * 128, col0 = blockIdx.x * 128;

  f32x4 acc[4][4] = {};

  const int srow = tid >> 3;
  const int scb = ((tid & 7) << 4) ^ ((srow & 7) << 4);
  const long aoff = (long)(row0 + srow) * K + (scb >> 1);
  const long boff = (long)(col0 + srow) * K + (scb >> 1);

  for (int k0 = 0; k0 < K; k0 += 64) {
    #pragma unroll
    for (int i = 0; i < 4; ++i) {
      __builtin_amdgcn_global_load_lds(AS1C(A + aoff + (long)i * 32 * K + k0),
                                       AS3((char*)As + i * 4096 + w * 1024), 16, 0, 0);
      __builtin_amdgcn_global_load_lds(AS1C(BT + boff + (long)i * 32 * K + k0),
                                       AS3((char*)Bs + i * 4096 + w * 1024), 16, 0, 0);
    }
    __syncthreads();
    #pragma unroll
    for (int kf = 0; kf < 2; ++kf) {
      bf16x8 af[4], bfr[4];
      #pragma unroll
      for (int m = 0; m < 4; ++m) {
        int r = wm * 64 + m * 16 + (lane & 15);
        int cb = (kf * 64 + ((lane >> 4) << 4)) ^ ((r & 7) << 4);
        af[m] = *reinterpret_cast<const bf16x8*>((const char*)As + r * 128 + cb);
      }
      #pragma unroll
      for (int n = 0; n < 4; ++n) {
        int r = wn * 64 + n * 16 + (lane & 15);
        int cb = (kf * 64 + ((lane >> 4) << 4)) ^ ((r & 7) << 4);
        bfr[n] = *reinterpret_cast<const bf16x8*>((const char*)Bs + r * 128 + cb);
      }
      #pragma unroll
      for (int m = 0; m < 4; ++m)
        #pragma unroll
        for (int n = 0; n < 4; ++n) {
          if constexpr (MODE == 1)
            acc[m][n] = __builtin_amdgcn_mfma_f32_16x16x32_bf16(bfr[n], af[m], acc[m][n], 0, 0, 0);
          else
            acc[m][n] = __builtin_amdgcn_mfma_f32_16x16x32_bf16(af[m], bfr[n], acc[m][n], 0, 0, 0);
        }
    }
    __syncthreads();
  }

  const int g = lane >> 4, q = lane & 15;

  if constexpr (MODE == 0) {
    #pragma unroll
    for (int m = 0; m < 4; ++m)
      #pragma unroll
      for (int n = 0; n < 4; ++n)
        #pragma unroll
        for (int r = 0; r < 4; ++r) {
          int grow = row0 + wm * 64 + m * 16 + g * 4 + r;
          int gcol = col0 + wn * 64 + n * 16 + q;
          reinterpret_cast<float*>(Cout)[(long)grow * N + gcol] = acc[m][n][r] + bias[gcol];
        }
  } else if constexpr (MODE == 1) {
    const int t = (int)blockIdx.x >> 3;                  // 0=Q, 1=K
    const int h = (((int)blockIdx.x << 1) | wn) & 15;
    const float qs = (t == 0) ? 0.125f * 1.44269504f : 1.0f;  // log2e folded into Q
    bf16* outb = reinterpret_cast<bf16*>(Cout) + (t ? 8388608 : 0);
    #pragma unroll
    for (int n = 0; n < 4; ++n) {
      f32x4 bv = *reinterpret_cast<const f32x4*>(bias + col0 + wn * 64 + n * 16 + g * 4);
      #pragma unroll
      for (int m = 0; m < 4; ++m) {
        int grow = row0 + wm * 64 + m * 16 + q;
        int bb = grow >> 11, ll = grow & 2047;
        bf16x4 o;
        #pragma unroll
        for (int r = 0; r < 4; ++r) o[r] = (bf16)((acc[m][n][r] + bv[r]) * qs);
        *reinterpret_cast<bf16x4*>(outb + ((long)(bb * 16 + h) * 2048 + ll) * 64 + n * 16 + g * 4) = o;
      }
    }
  } else {
    const int h = (((int)blockIdx.x << 1) | wn) & 15;
    bf16* outb = reinterpret_cast<bf16*>(Cout);
    #pragma unroll
    for (int n = 0; n < 4; ++n) {
      float bv = bias[col0 + wn * 64 + n * 16 + q];
      int hd = n * 16 + q;
      #pragma unroll
      for (int m = 0; m < 4; ++m) {
        int grow = row0 + wm * 64 + m * 16 + g * 4;
        int bb = grow >> 11, ll = grow & 2047;
        bf16x4 o;
        #pragma unroll
        for (int r = 0; r < 4; ++r) o[r] = (bf16)(acc[m][n][r] + bv);
        *reinterpret_cast<bf16x4*>(outb + ((long)(bb * 16 + h) * 64 + hd) * 2048 + ll) = o;
      }
    }
  }
}

// ---------------- causal flash attention: r4 structure + counted vmcnt (T4) --
// Q,K: [bh][2048][64] bf16 (Q pre-scaled by 0.125*log2e). VT: [bh][64][2048].
// Grid 2048 x 256thr, 4 waves x 16 q-rows. K/V TRIPLE-buffered LDS (48KB);
// per tile: s_waitcnt vmcnt(4) + raw s_barrier (stage(kt+1) stays in flight),
// then issue stage(kt+2) -> each stage gets 2 compute phases to land.
__global__ __launch_bounds__(256, 4)
void attn_fwd(const bf16* __restrict__ Qg, const bf16* __restrict__ Kg,
              const bf16* __restrict__ VTg, bf16* __restrict__ Og) {
  __shared__ bf16 Ks[3][64 * 64];   // 24KB
  __shared__ bf16 Vs[3][64 * 64];   // 24KB
  const int tid = threadIdx.x, lane = tid & 63, w = tid >> 6;
  const int g = lane >> 4, q = lane & 15;

  const int orig = blockIdx.x;
  const int wgid = (orig & 7) * 256 + (orig >> 3);   // XCD-chunked bijective
  const int bh = wgid >> 5;
  const int qt = 31 - (wgid & 31);                   // heavy q-tiles first
  const int bb = bh >> 4, h = bh & 15;
  const long base = (long)bh * (2048 * 64);
  const int qw = qt * 64 + w * 16;
  const int myq = qw + q;
  const int nt = qt + 1;

  bf16x8 qf[2];
  qf[0] = *reinterpret_cast<const bf16x8*>(Qg + base + (long)myq * 64 + g * 8);
  qf[1] = *reinterpret_cast<const bf16x8*>(Qg + base + (long)myq * 64 + 32 + g * 8);

  f32x4 accO[4] = {};
  float m = -1e30f, l = 0.f;

  const int srow = tid >> 3;
  const int scb = ((tid & 7) << 4) ^ ((srow & 7) << 4);

  auto stage = [&](int kt, int buf) {   // exactly 4 gload_lds per wave
    #pragma unroll
    for (int i = 0; i < 2; ++i) {
      __builtin_amdgcn_global_load_lds(
          AS1C(Kg + base + (long)(kt * 64 + i * 32 + srow) * 64 + (scb >> 1)),
          AS3((char*)&Ks[buf][0] + i * 4096 + w * 1024), 16, 0, 0);
      __builtin_amdgcn_global_load_lds(
          AS1C(VTg + base + (long)(i * 32 + srow) * 2048 + kt * 64 + (scb >> 1)),
          AS3((char*)&Vs[buf][0] + i * 4096 + w * 1024), 16, 0, 0);
    }
  };

  // prologue: 2 tiles in flight
  stage(0, 0);
  stage(nt > 1 ? 1 : 0, 1);
  asm volatile("" ::: "memory");

  for (int kt = 0; kt < nt; ++kt) {
    const int cur = kt % 3;
    // stage(kt) complete; stage(kt+1)'s 4 loads stay outstanding (never drain 0)
    asm volatile("s_waitcnt vmcnt(4)" ::: "memory");
    __builtin_amdgcn_s_barrier();
    { int nk = kt + 2 < nt ? kt + 2 : nt - 1;   // clamped: dead writes to unread buf
      stage(nk, (kt + 2) % 3); }
    asm volatile("" ::: "memory");

    const char* Kb = (const char*)&Ks[cur][0];
    const char* Vb = (const char*)&Vs[cur][0];

    f32x4 sT[4] = {};
    #pragma unroll
    for (int kf = 0; kf < 2; ++kf) {
      #pragma unroll
      for (int a = 0; a < 4; ++a) {
        int r = a * 16 + q;
        int cb = (kf * 64 + g * 16) ^ ((r & 7) << 4);
        bf16x8 kb = *reinterpret_cast<const bf16x8*>(Kb + r * 128 + cb);
        sT[a] = __builtin_amdgcn_mfma_f32_16x16x32_bf16(kb, qf[kf], sT[a], 0, 0, 0);
      }
    }

    if (kt == qt) {
      #pragma unroll
      for (int a = 0; a < 4; ++a)
        #pragma unroll
        for (int r = 0; r < 4; ++r) {
          int kv = kt * 64 + a * 16 + 4 * g + r;
          if (kv > myq) sT[a][r] = -1e30f;
        }
    }

    // max via max3 tree + 2-step butterfly (log2 domain)
    float t0 = m3(sT[0][0], sT[0][1], sT[0][2]);
    float t1 = m3(sT[0][3], sT[1][0], sT[1][1]);
    float t2 = m3(sT[1][2], sT[1][3], sT[2][0]);
    float t3 = m3(sT[2][1], sT[2][2], sT[2][3]);
    float t4 = m3(sT[3][0], sT[3][1], sT[3][2]);
    float vm = fmaxf(m3(t0, t1, t2), m3(t3, t4, sT[3][3]));
    vm = fmaxf(vm, __shfl_xor(vm, 16));
    vm = fmaxf(vm, __shfl_xor(vm, 32));
    float mnew = fmaxf(m, vm);
    float fac = fexp2(m - mnew);
    m = mnew;

    float ps = 0.f;
    bf16x4 pa[4];
    #pragma unroll
    for (int a = 0; a < 4; ++a)
      #pragma unroll
      for (int r = 0; r < 4; ++r) {
        float p = fexp2(sT[a][r] - mnew);
        ps += p;
        pa[a][r] = (bf16)p;
      }
    ps += __shfl_xor(ps, 16);
    ps += __shfl_xor(ps, 32);
    l = l * fac + ps;
    #pragma unroll
    for (int b = 0; b < 4; ++b) accO[b] *= fac;

    #pragma unroll
    for (int a = 0; a < 4; ++a) {
      #pragma unroll
      for (int b = 0; b < 4; ++b) {
        int row = b * 16 + q;
        int cb = (a * 32 + g * 8) ^ ((row & 7) << 4);
        bf16x4 vfrag = *reinterpret_cast<const bf16x4*>(Vb + row * 128 + cb);
        accO[b] = pv_mfma(vfrag, pa[a], accO[b]);
      }
    }
  }

  // drain outstanding clamped stages, then reuse Ks[0] for the transpose
  asm volatile("s_waitcnt vmcnt(0)" ::: "memory");
  __syncthreads();
  char* ob = (char*)&Ks[0][0] + w * 2048;
  float rl = 1.0f / l;
  #pragma unroll
  for (int b = 0; b < 4; ++b)
    #pragma unroll
    for (int r = 0; r < 4; ++r) {
      int hd = 16 * b + 4 * g + r;
      int cb = (hd * 2) ^ ((q & 7) << 4);
      *reinterpret_cast<bf16*>(ob + q * 128 + cb) = (bf16)(accO[b][r] * rl);
    }
  asm volatile("s_waitcnt lgkmcnt(0)" ::: "memory");
  __builtin_amdgcn_sched_barrier(0);

  const int rr = lane >> 2, cc = lane & 3;
  #pragma unroll
  for (int half = 0; half < 2; ++half) {
    int hd0 = cc * 16 + half * 8;
    int cb = (hd0 * 2) ^ ((rr & 7) << 4);
    bf16x8 vv = *reinterpret_cast<const bf16x8*>(ob + rr * 128 + cb);
    *reinterpret_cast<bf16x8*>(Og + (long)(bb * 2048 + qw + rr) * 1024 + h * 64 + hd0) = vv;
  }
}

// ---------------- launch ----------------
extern "C" void kernel_launch(void* const* d_in, const int* in_sizes, int n_in,
                              void* d_out, int out_size, void* d_ws, size_t ws_size,
                              hipStream_t stream) {
  (void)in_sizes; (void)n_in; (void)out_size; (void)ws_size;
  const float* x     = (const float*)d_in[0];
  const float* Wqkv  = (const float*)d_in[3];
  const float* bqkv  = (const float*)d_in[4];
  const float* Wproj = (const float*)d_in[5];
  const float* bproj = (const float*)d_in[6];

  bf16* xb     = (bf16*)d_ws;              // 8192*1024
  bf16* Wqkvb  = xb + 8388608;             // 3072*1024
  bf16* Wprojb = Wqkvb + 3145728;          // 1024*1024
  bf16* Qb     = Wprojb + 1048576;         // Q | K | VT : 3 * 8388608
  bf16* Ob     = Qb + 3 * 8388608;         // 8192*1024

  castk<<<8192, 256, 0, stream>>>(x, xb, 8388608);
  castk<<<3072, 256, 0, stream>>>(Wqkv, Wqkvb, 3145728);
  castk<<<1024, 256, 0, stream>>>(Wproj, Wprojb, 1048576);

  // QKV GEMM split (verified r4 config): Q,K (swapped) | V -> VT (original)
  gemm_bt<1><<<dim3(16, 64), 256, 0, stream>>>(xb, Wqkvb, bqkv, (void*)Qb, 8192, 3072, 1024);
  gemm_bt<2><<<dim3(8, 64), 256, 0, stream>>>(xb, Wqkvb + (long)2048 * 1024, bqkv + 2048,
                                              (void*)(Qb + 16777216), 8192, 3072, 1024);

  // attention: 2048 blocks (32 q-tiles x 64 bh), XCD-swizzled, counted-vmcnt
  attn_fwd<<<dim3(2048), 256, 0, stream>>>(Qb, Qb + 8388608, Qb + 16777216, Ob);

  // proj GEMM: M=8192, N=1024, K=1024 -> f32 d_out
  gemm_bt<0><<<dim3(8, 64), 256, 0, stream>>>(Ob, Wprojb, bproj, d_out, 8192, 1024, 1024);
}

// Round 15
// 194.248 us; speedup vs baseline: 1.1741x; 1.0370x over previous
//
#include <hip/hip_runtime.h>

typedef __bf16 bf16;
typedef __attribute__((ext_vector_type(8))) __bf16 bf16x8;
typedef __attribute__((ext_vector_type(4))) __bf16 bf16x4;
typedef __attribute__((ext_vector_type(4))) float f32x4;
typedef __attribute__((ext_vector_type(4))) short short4v;

#define AS1C(p) ((const __attribute__((address_space(1))) void*)(p))
#define AS3(p)  ((__attribute__((address_space(3))) void*)(p))

static __device__ __forceinline__ f32x4 pv_mfma(bf16x4 a, bf16x4 b, f32x4 c) {
#if __has_builtin(__builtin_amdgcn_mfma_f32_16x16x16bf16_1k)
  return __builtin_amdgcn_mfma_f32_16x16x16bf16_1k(
      __builtin_bit_cast(short4v, a), __builtin_bit_cast(short4v, b), c, 0, 0, 0);
#else
  f32x4 d = c;
  asm("v_mfma_f32_16x16x16_bf16 %0, %1, %2, %0" : "+v"(d) : "v"(a), "v"(b));
  return d;
#endif
}

static __device__ __forceinline__ float fexp2(float x) {
#if __has_builtin(__builtin_amdgcn_exp2f)
  return __builtin_amdgcn_exp2f(x);
#else
  return exp2f(x);
#endif
}
static __device__ __forceinline__ float m3(float a, float b, float c) {
  return fmaxf(fmaxf(a, b), c);
}

// ---------------- cast f32 -> bf16, vectorized ----------------
__global__ void castk(const float* __restrict__ in, bf16* __restrict__ out, long n) {
  long i = ((long)blockIdx.x * blockDim.x + threadIdx.x) * 4;
  if (i >= n) return;
  f32x4 v = *reinterpret_cast<const f32x4*>(in + i);
  bf16x4 o;
  o[0] = (bf16)v[0]; o[1] = (bf16)v[1]; o[2] = (bf16)v[2]; o[3] = (bf16)v[3];
  *reinterpret_cast<bf16x4*>(out + i) = o;
}

// ---------------- GEMM: C = A * BT^T + bias (verified r4 structure, 128^2) ---
// MODE 0: proj -> f32 C[M][N]. MODE 1: Q,K -> [bh][l][hd] (Q scaled 0.125*log2e).
// MODE 2: V -> VT [bh][hd][2048].
template<int MODE>
__global__ __launch_bounds__(256, 2)
void gemm_bt(const bf16* __restrict__ A, const bf16* __restrict__ BT,
             const float* __restrict__ bias, void* __restrict__ Cout,
             int M, int N, int K) {
  __shared__ bf16 As[128 * 64];
  __shared__ bf16 Bs[128 * 64];
  const int tid = threadIdx.x;
  const int lane = tid & 63;
  const int w = tid >> 6;
  const int wm = w >> 1, wn = w & 1;
  const int row0 = blockIdx.y * 128, col0 = blockIdx.x * 128;

  f32x4 acc[4][4] = {};

  const int srow = tid >> 3;
  const int scb = ((tid & 7) << 4) ^ ((srow & 7) << 4);
  const long aoff = (long)(row0 + srow) * K + (scb >> 1);
  const long boff = (long)(col0 + srow) * K + (scb >> 1);

  for (int k0 = 0; k0 < K; k0 += 64) {
    #pragma unroll
    for (int i = 0; i < 4; ++i) {
      __builtin_amdgcn_global_load_lds(AS1C(A + aoff + (long)i * 32 * K + k0),
                                       AS3((char*)As + i * 4096 + w * 1024), 16, 0, 0);
      __builtin_amdgcn_global_load_lds(AS1C(BT + boff + (long)i * 32 * K + k0),
                                       AS3((char*)Bs + i * 4096 + w * 1024), 16, 0, 0);
    }
    __syncthreads();
    #pragma unroll
    for (int kf = 0; kf < 2; ++kf) {
      bf16x8 af[4], bfr[4];
      #pragma unroll
      for (int m = 0; m < 4; ++m) {
        int r = wm * 64 + m * 16 + (lane & 15);
        int cb = (kf * 64 + ((lane >> 4) << 4)) ^ ((r & 7) << 4);
        af[m] = *reinterpret_cast<const bf16x8*>((const char*)As + r * 128 + cb);
      }
      #pragma unroll
      for (int n = 0; n < 4; ++n) {
        int r = wn * 64 + n * 16 + (lane & 15);
        int cb = (kf * 64 + ((lane >> 4) << 4)) ^ ((r & 7) << 4);
        bfr[n] = *reinterpret_cast<const bf16x8*>((const char*)Bs + r * 128 + cb);
      }
      #pragma unroll
      for (int m = 0; m < 4; ++m)
        #pragma unroll
        for (int n = 0; n < 4; ++n) {
          if constexpr (MODE == 1)
            acc[m][n] = __builtin_amdgcn_mfma_f32_16x16x32_bf16(bfr[n], af[m], acc[m][n], 0, 0, 0);
          else
            acc[m][n] = __builtin_amdgcn_mfma_f32_16x16x32_bf16(af[m], bfr[n], acc[m][n], 0, 0, 0);
        }
    }
    __syncthreads();
  }

  const int g = lane >> 4, q = lane & 15;

  if constexpr (MODE == 0) {
    #pragma unroll
    for (int m = 0; m < 4; ++m)
      #pragma unroll
      for (int n = 0; n < 4; ++n)
        #pragma unroll
        for (int r = 0; r < 4; ++r) {
          int grow = row0 + wm * 64 + m * 16 + g * 4 + r;
          int gcol = col0 + wn * 64 + n * 16 + q;
          reinterpret_cast<float*>(Cout)[(long)grow * N + gcol] = acc[m][n][r] + bias[gcol];
        }
  } else if constexpr (MODE == 1) {
    const int t = (int)blockIdx.x >> 3;                  // 0=Q, 1=K
    const int h = (((int)blockIdx.x << 1) | wn) & 15;
    const float qs = (t == 0) ? 0.125f * 1.44269504f : 1.0f;  // log2e folded into Q
    bf16* outb = reinterpret_cast<bf16*>(Cout) + (t ? 8388608 : 0);
    #pragma unroll
    for (int n = 0; n < 4; ++n) {
      f32x4 bv = *reinterpret_cast<const f32x4*>(bias + col0 + wn * 64 + n * 16 + g * 4);
      #pragma unroll
      for (int m = 0; m < 4; ++m) {
        int grow = row0 + wm * 64 + m * 16 + q;
        int bb = grow >> 11, ll = grow & 2047;
        bf16x4 o;
        #pragma unroll
        for (int r = 0; r < 4; ++r) o[r] = (bf16)((acc[m][n][r] + bv[r]) * qs);
        *reinterpret_cast<bf16x4*>(outb + ((long)(bb * 16 + h) * 2048 + ll) * 64 + n * 16 + g * 4) = o;
      }
    }
  } else {
    const int h = (((int)blockIdx.x << 1) | wn) & 15;
    bf16* outb = reinterpret_cast<bf16*>(Cout);
    #pragma unroll
    for (int n = 0; n < 4; ++n) {
      float bv = bias[col0 + wn * 64 + n * 16 + q];
      int hd = n * 16 + q;
      #pragma unroll
      for (int m = 0; m < 4; ++m) {
        int grow = row0 + wm * 64 + m * 16 + g * 4;
        int bb = grow >> 11, ll = grow & 2047;
        bf16x4 o;
        #pragma unroll
        for (int r = 0; r < 4; ++r) o[r] = (bf16)(acc[m][n][r] + bv);
        *reinterpret_cast<bf16x4*>(outb + ((long)(bb * 16 + h) * 64 + hd) * 2048 + ll) = o;
      }
    }
  }
}

// ---------------- causal flash attention: r13 structure + defer-max + setprio -
// Q,K: [bh][2048][64] bf16 (Q pre-scaled by 0.125*log2e). VT: [bh][64][2048].
// Grid 2048 x 256thr, 4 waves x 16 q-rows, K/V double-buffered LDS,
// one __syncthreads per tile, stage issued right after barrier (verified best).
__global__ __launch_bounds__(256, 4)
void attn_fwd(const bf16* __restrict__ Qg, const bf16* __restrict__ Kg,
              const bf16* __restrict__ VTg, bf16* __restrict__ Og) {
  __shared__ bf16 Ks[2][64 * 64];
  __shared__ bf16 Vs[2][64 * 64];
  const int tid = threadIdx.x, lane = tid & 63, w = tid >> 6;
  const int g = lane >> 4, q = lane & 15;

  const int orig = blockIdx.x;
  const int wgid = (orig & 7) * 256 + (orig >> 3);   // XCD-chunked bijective
  const int bh = wgid >> 5;
  const int qt = 31 - (wgid & 31);                   // heavy q-tiles first
  const int bb = bh >> 4, h = bh & 15;
  const long base = (long)bh * (2048 * 64);
  const int qw = qt * 64 + w * 16;
  const int myq = qw + q;
  const int nt = qt + 1;

  bf16x8 qf[2];
  qf[0] = *reinterpret_cast<const bf16x8*>(Qg + base + (long)myq * 64 + g * 8);
  qf[1] = *reinterpret_cast<const bf16x8*>(Qg + base + (long)myq * 64 + 32 + g * 8);

  f32x4 accO[4] = {};
  float m = -1e30f, l = 0.f;

  const int srow = tid >> 3;
  const int scb = ((tid & 7) << 4) ^ ((srow & 7) << 4);

  auto stage = [&](int kt, int buf) {
    #pragma unroll
    for (int i = 0; i < 2; ++i) {
      __builtin_amdgcn_global_load_lds(
          AS1C(Kg + base + (long)(kt * 64 + i * 32 + srow) * 64 + (scb >> 1)),
          AS3((char*)&Ks[buf][0] + i * 4096 + w * 1024), 16, 0, 0);
      __builtin_amdgcn_global_load_lds(
          AS1C(VTg + base + (long)(i * 32 + srow) * 2048 + kt * 64 + (scb >> 1)),
          AS3((char*)&Vs[buf][0] + i * 4096 + w * 1024), 16, 0, 0);
    }
  };

  stage(0, 0);

  for (int kt = 0; kt < nt; ++kt) {
    const int cur = kt & 1;
    __syncthreads();                          // stage(kt) landed
    if (kt + 1 < nt) stage(kt + 1, cur ^ 1);  // prefetch: full compute phase to land

    const char* Kb = (const char*)&Ks[cur][0];
    const char* Vb = (const char*)&Vs[cur][0];

    // S^T[kv][q]: lane owns q-row myq, kv = a*16 + 4g + r
    f32x4 sT[4] = {};
    __builtin_amdgcn_s_setprio(1);
    #pragma unroll
    for (int kf = 0; kf < 2; ++kf) {
      #pragma unroll
      for (int a = 0; a < 4; ++a) {
        int r = a * 16 + q;
        int cb = (kf * 64 + g * 16) ^ ((r & 7) << 4);
        bf16x8 kb = *reinterpret_cast<const bf16x8*>(Kb + r * 128 + cb);
        sT[a] = __builtin_amdgcn_mfma_f32_16x16x32_bf16(kb, qf[kf], sT[a], 0, 0, 0);
      }
    }
    __builtin_amdgcn_s_setprio(0);

    if (kt == qt) {
      #pragma unroll
      for (int a = 0; a < 4; ++a)
        #pragma unroll
        for (int r = 0; r < 4; ++r) {
          int kv = kt * 64 + a * 16 + 4 * g + r;
          if (kv > myq) sT[a][r] = -1e30f;
        }
    }

    // max via max3 tree + 2-step butterfly (log2 domain)
    float t0 = m3(sT[0][0], sT[0][1], sT[0][2]);
    float t1 = m3(sT[0][3], sT[1][0], sT[1][1]);
    float t2 = m3(sT[1][2], sT[1][3], sT[2][0]);
    float t3 = m3(sT[2][1], sT[2][2], sT[2][3]);
    float t4 = m3(sT[3][0], sT[3][1], sT[3][2]);
    float vm = fmaxf(m3(t0, t1, t2), m3(t3, t4, sT[3][3]));
    vm = fmaxf(vm, __shfl_xor(vm, 16));
    vm = fmaxf(vm, __shfl_xor(vm, 32));

    // defer-max (T13): rescale only when max grew by >8 (fac==1 exactly otherwise)
    if (__ballot(vm > m + 8.0f)) {
      float mnew = fmaxf(m, vm);
      float fac = fexp2(m - mnew);
      m = mnew;
      l *= fac;
      #pragma unroll
      for (int b = 0; b < 4; ++b) accO[b] *= fac;
    }

    float ps = 0.f;
    bf16x4 pa[4];
    #pragma unroll
    for (int a = 0; a < 4; ++a)
      #pragma unroll
      for (int r = 0; r < 4; ++r) {
        float p = fexp2(sT[a][r] - m);
        ps += p;
        pa[a][r] = (bf16)p;
      }
    ps += __shfl_xor(ps, 16);
    ps += __shfl_xor(ps, 32);
    l += ps;

    // O^T += V^T * P^T (P^T frag already in B-layout, zero cross-lane movement)
    __builtin_amdgcn_s_setprio(1);
    #pragma unroll
    for (int a = 0; a < 4; ++a) {
      #pragma unroll
      for (int b = 0; b < 4; ++b) {
        int row = b * 16 + q;
        int cb = (a * 32 + g * 8) ^ ((row & 7) << 4);
        bf16x4 vfrag = *reinterpret_cast<const bf16x4*>(Vb + row * 128 + cb);
        accO[b] = pv_mfma(vfrag, pa[a], accO[b]);
      }
    }
    __builtin_amdgcn_s_setprio(0);
  }

  // epilogue: normalize, transpose O^T -> O via LDS (reuse Ks[0]), store coalesced
  __syncthreads();
  char* ob = (char*)&Ks[0][0] + w * 2048;
  float rl = 1.0f / l;
  #pragma unroll
  for (int b = 0; b < 4; ++b)
    #pragma unroll
    for (int r = 0; r < 4; ++r) {
      int hd = 16 * b + 4 * g + r;
      int cb = (hd * 2) ^ ((q & 7) << 4);
      *reinterpret_cast<bf16*>(ob + q * 128 + cb) = (bf16)(accO[b][r] * rl);
    }
  asm volatile("s_waitcnt lgkmcnt(0)" ::: "memory");
  __builtin_amdgcn_sched_barrier(0);

  const int rr = lane >> 2, cc = lane & 3;
  #pragma unroll
  for (int half = 0; half < 2; ++half) {
    int hd0 = cc * 16 + half * 8;
    int cb = (hd0 * 2) ^ ((rr & 7) << 4);
    bf16x8 vv = *reinterpret_cast<const bf16x8*>(ob + rr * 128 + cb);
    *reinterpret_cast<bf16x8*>(Og + (long)(bb * 2048 + qw + rr) * 1024 + h * 64 + hd0) = vv;
  }
}

// ---------------- launch ----------------
extern "C" void kernel_launch(void* const* d_in, const int* in_sizes, int n_in,
                              void* d_out, int out_size, void* d_ws, size_t ws_size,
                              hipStream_t stream) {
  (void)in_sizes; (void)n_in; (void)out_size; (void)ws_size;
  const float* x     = (const float*)d_in[0];
  const float* Wqkv  = (const float*)d_in[3];
  const float* bqkv  = (const float*)d_in[4];
  const float* Wproj = (const float*)d_in[5];
  const float* bproj = (const float*)d_in[6];

  bf16* xb     = (bf16*)d_ws;              // 8192*1024
  bf16* Wqkvb  = xb + 8388608;             // 3072*1024
  bf16* Wprojb = Wqkvb + 3145728;          // 1024*1024
  bf16* Qb     = Wprojb + 1048576;         // Q | K | VT : 3 * 8388608
  bf16* Ob     = Qb + 3 * 8388608;         // 8192*1024

  castk<<<8192, 256, 0, stream>>>(x, xb, 8388608);
  castk<<<3072, 256, 0, stream>>>(Wqkv, Wqkvb, 3145728);
  castk<<<1024, 256, 0, stream>>>(Wproj, Wprojb, 1048576);

  // QKV GEMM split (verified r4 config): Q,K (swapped) | V -> VT (original)
  gemm_bt<1><<<dim3(16, 64), 256, 0, stream>>>(xb, Wqkvb, bqkv, (void*)Qb, 8192, 3072, 1024);
  gemm_bt<2><<<dim3(8, 64), 256, 0, stream>>>(xb, Wqkvb + (long)2048 * 1024, bqkv + 2048,
                                              (void*)(Qb + 16777216), 8192, 3072, 1024);

  // attention: 2048 blocks (32 q-tiles x 64 bh), XCD-swizzled (verified structure)
  attn_fwd<<<dim3(2048), 256, 0, stream>>>(Qb, Qb + 8388608, Qb + 16777216, Ob);

  // proj GEMM: M=8192, N=1024, K=1024 -> f32 d_out
  gemm_bt<0><<<dim3(8, 64), 256, 0, stream>>>(Ob, Wprojb, bproj, d_out, 8192, 1024, 1024);
}